// Round 7
// baseline (177.970 us; speedup 1.0000x reference)
//
#include <hip/hip_runtime.h>
#include <math.h>

// Problem constants (match reference)
constexpr int D_ = 64;
constexpr int N_ = 8192;
constexpr int DIM_ = 256;
constexpr int K_ = 32;
constexpr int L_ = 1;
constexpr int P_ = D_ - L_;  // 63
constexpr float TEMP_ = 0.1f;
constexpr float EPS_ = 1e-8f;

constexpr int CHUNKS = 32;   // blocks per d
constexpr int CROWS = 256;   // rows per chunk (per block)
constexpr int BATCH = 16;    // rows per wave per LDS round
constexpr int LDSTR = 65;    // scratch stride (words) -> 2-way (free) banks

typedef unsigned long long u64;
typedef float f32x4 __attribute__((ext_vector_type(4)));  // native vec for nontemporal

// Kernel 1: streaming colsums + per-block sorted top-32 candidates.
// Block (d, chunk) covers rows [chunk*256, chunk*256+256). Waves read rows
// round-robin (row = 4*k + wave) so the block advances one tight 256KB
// sequential stream. Row-norm keys (normbits<<32 | N-1-n) collect in LDS;
// a 256-element bitonic sort (desc) emits the block's sorted top-32.
// Colsums go to per-chunk partial buffers (plain stores, no atomics).
__global__ __launch_bounds__(256) void k1_stream(const float* __restrict__ emb,
                                                 u64* __restrict__ cand,
                                                 float* __restrict__ psum) {
  const int b = blockIdx.x;
  const int d = b >> 5;
  const int chunk = b & 31;
  const int tid = threadIdx.x;
  const int wave = tid >> 6;
  const int lane = tid & 63;
  const float* base = emb + (size_t)d * N_ * DIM_;

  __shared__ union {
    float scr[4][BATCH * LDSTR];  // 16.25 KB (streaming scratch)
    float stash[4][DIM_];         // 4 KB (colsum combine)
  } u;
  __shared__ u64 keys[CROWS];     // 2 KB

  float a0 = 0.f, a1 = 0.f, a2 = 0.f, a3 = 0.f;

  for (int bt = 0; bt < CROWS / (4 * BATCH); ++bt) {
#pragma unroll
    for (int r = 0; r < BATCH; ++r) {
      const int krow = bt * BATCH + r;
      const int grow = chunk * CROWS + (krow << 2) + wave;  // stride-4 interleave
      const f32x4 v = __builtin_nontemporal_load(
          reinterpret_cast<const f32x4*>(base + (size_t)grow * DIM_ + (lane << 2)));
      a0 += v.x; a1 += v.y; a2 += v.z; a3 += v.w;
      u.scr[wave][r * LDSTR + lane] = v.x * v.x + v.y * v.y + v.z * v.z + v.w * v.w;
    }
    // Own-wave transpose-reduce: 4 lanes per row x 16 rows.
    {
      const int r2 = lane >> 2, q = lane & 3;
      const float* p = &u.scr[wave][r2 * LDSTR + q * 16];
      float s = 0.f;
#pragma unroll
      for (int i = 0; i < 16; ++i) s += p[i];
      s += __shfl_xor(s, 1, 64);
      s += __shfl_xor(s, 2, 64);
      if (q == 0) {
        const int browid = ((bt * BATCH + r2) << 2) + wave;
        const int n = chunk * CROWS + browid;
        // larger norm wins; tie -> larger (N-1-n) = smaller index (stable argsort)
        keys[browid] = ((u64)__float_as_uint(s) << 32) | (unsigned)(N_ - 1 - n);
      }
    }
  }

  // Colsums: barrier first (stash aliases scr across waves), combine, store.
  __syncthreads();
  reinterpret_cast<float4*>(&u.stash[wave][0])[lane] = make_float4(a0, a1, a2, a3);
  __syncthreads();
  {
    const float cs = u.stash[0][tid] + u.stash[1][tid] + u.stash[2][tid] + u.stash[3][tid];
    psum[(size_t)(d * CHUNKS + chunk) * DIM_ + tid] = cs;
  }

  // Bitonic sort keys[256] descending (keys unique -> total order).
  for (int size = 2; size <= CROWS; size <<= 1) {
    for (int stride = size >> 1; stride > 0; stride >>= 1) {
      __syncthreads();
      const int partner = tid ^ stride;
      if (partner > tid) {
        const u64 a = keys[tid], c = keys[partner];
        const bool desc = ((tid & size) == 0);
        if (desc ? (a < c) : (a > c)) { keys[tid] = c; keys[partner] = a; }
      }
    }
  }
  __syncthreads();
  if (tid < K_) cand[(size_t)(d * CHUNKS + chunk) * K_ + tid] = keys[tid];
}

// Kernel 2+3: one block per d. Wave 0 merges the 32 sorted candidate lists
// (32 rounds, no barriers, keys unique so no ties); meanwhile all threads
// accumulate the per-chunk colsums. Then gather top-32 rows, form samples,
// normalize, write nS. Block 0 zeroes the loss accumulator.
__global__ __launch_bounds__(256) void k23_topk_samples(const float* __restrict__ emb,
                                                        const u64* __restrict__ cand,
                                                        const float* __restrict__ psum,
                                                        float* __restrict__ nS,
                                                        float* __restrict__ out) {
  const int d = blockIdx.x;
  const int tid = threadIdx.x;
  const int lane = tid & 63;
  const int wave = tid >> 6;

  __shared__ u64 ck[CHUNKS * K_];  // 8 KB
  __shared__ int top[K_];
  __shared__ float w1[4], w2[4];
  __shared__ float inv1s, inv2s;

  for (int i = tid; i < CHUNKS * K_; i += 256)
    ck[i] = cand[(size_t)d * CHUNKS * K_ + i];

  // Colsum (independent of the merge): s1[dim=tid] = sum over 32 chunks.
  float s1 = 0.f;
#pragma unroll 8
  for (int c = 0; c < CHUNKS; ++c)
    s1 += psum[(size_t)(d * CHUNKS + c) * DIM_ + tid];

  __syncthreads();  // ck ready

  if (wave == 0) {
    // lane c < 32 owns sorted list c; 32 rounds of head-max.
    int h = 0;
    u64 cur = (lane < CHUNKS) ? ck[lane * K_] : 0ull;
    for (int k = 0; k < K_; ++k) {
      u64 m = cur;
#pragma unroll
      for (int off = 1; off < 32; off <<= 1) {
        const u64 o = __shfl_xor(m, off, 64);
        if (o > m) m = o;
      }
      const u64 bal = __ballot(lane < CHUNKS && cur == m);
      const int w = __ffsll(bal) - 1;
      if (lane == 0) top[k] = N_ - 1 - (int)(m & 0xFFFFFFFFull);
      if (lane == w) { ++h; cur = (h < K_) ? ck[lane * K_ + h] : 0ull; }
    }
  }
  __syncthreads();

  // Gather + samples + normalize.
  const float* base = emb + (size_t)d * N_ * DIM_;
  float ts = 0.f;
#pragma unroll 4
  for (int k = 0; k < K_; ++k) ts += base[(size_t)top[k] * DIM_ + tid];
  const float s2 = s1 - ts;

  float q1 = s1 * s1, q2 = s2 * s2;
#pragma unroll
  for (int off = 32; off > 0; off >>= 1) {
    q1 += __shfl_down(q1, off, 64);
    q2 += __shfl_down(q2, off, 64);
  }
  if (lane == 0) { w1[wave] = q1; w2[wave] = q2; }
  __syncthreads();
  if (tid == 0) {
    const float n1 = sqrtf(w1[0] + w1[1] + w1[2] + w1[3]);
    const float n2 = sqrtf(w2[0] + w2[1] + w2[2] + w2[3]);
    inv1s = 1.0f / fmaxf(n1, EPS_);
    inv2s = 1.0f / fmaxf(n2, EPS_);
    if (d == 0) out[0] = 0.0f;  // zero loss accumulator (ordered before k4)
  }
  __syncthreads();
  nS[d * DIM_ + tid] = s1 * inv1s;
  nS[(D_ + d) * DIM_ + tid] = s2 * inv2s;
}

// Loss kernel: 4 waves per pair; wave w handles 8 negatives for both sides
// with an online (max, sumexp) held uniformly in all lanes, combined via LDS.
__global__ __launch_bounds__(256) void k4_loss(const float* __restrict__ nS,
                                               const int* __restrict__ negidx,
                                               float* __restrict__ out) {
  const int p = blockIdx.x;
  const int tid = threadIdx.x;
  const int wave = tid >> 6;
  const int lane = tid & 63;

  const float4 vi = *reinterpret_cast<const float4*>(nS + p * DIM_ + (lane << 2));
  const float4 vj = *reinterpret_cast<const float4*>(nS + (p + L_) * DIM_ + (lane << 2));

  float dp = vi.x * vj.x + vi.y * vj.y + vi.z * vj.z + vi.w * vj.w;
#pragma unroll
  for (int off = 1; off < 64; off <<= 1) dp += __shfl_xor(dp, off, 64);
  const float invT = 1.0f / TEMP_;
  const float posT = dp * invT;

  float mi = -INFINITY, si = 0.f, mj = -INFINITY, sj = 0.f;
#pragma unroll
  for (int kk = 0; kk < K_ / 4; ++kk) {
    const int k = wave * (K_ / 4) + kk;
    const int idx = negidx[p * K_ + k];
    const float4 vn = *reinterpret_cast<const float4*>(nS + idx * DIM_ + (lane << 2));
    float di = vi.x * vn.x + vi.y * vn.y + vi.z * vn.z + vi.w * vn.w;
    float dj = vj.x * vn.x + vj.y * vn.y + vj.z * vn.z + vj.w * vn.w;
#pragma unroll
    for (int off = 1; off < 64; off <<= 1) {
      di += __shfl_xor(di, off, 64);
      dj += __shfl_xor(dj, off, 64);
    }
    const float li = di * invT;
    const float lj = dj * invT;
    if (li > mi) { si = si * expf(mi - li) + 1.f; mi = li; } else { si += expf(li - mi); }
    if (lj > mj) { sj = sj * expf(mj - lj) + 1.f; mj = lj; } else { sj += expf(lj - mj); }
  }

  __shared__ float pm[2][4], ps[2][4];
  if (lane == 0) {
    pm[0][wave] = mi; ps[0][wave] = si;
    pm[1][wave] = mj; ps[1][wave] = sj;
  }
  __syncthreads();
  if (tid == 0) {
    float total = 0.f;
#pragma unroll
    for (int side = 0; side < 2; ++side) {
      float m = posT;
      for (int w = 0; w < 4; ++w) m = fmaxf(m, pm[side][w]);
      float s = expf(posT - m);
      for (int w = 0; w < 4; ++w) s += ps[side][w] * expf(pm[side][w] - m);
      total += m + logf(s) - posT;  // lse - posT
    }
    atomicAdd(out, total / (2.0f * P_));
  }
}

extern "C" void kernel_launch(void* const* d_in, const int* in_sizes, int n_in,
                              void* d_out, int out_size, void* d_ws, size_t ws_size,
                              hipStream_t stream) {
  const float* emb = (const float*)d_in[0];
  const int* negidx = (const int*)d_in[1];
  float* out = (float*)d_out;

  // Workspace layout:
  u64* cand = (u64*)d_ws;                                   // 64*32*32 u64 = 512 KB
  float* psum = (float*)(cand + (size_t)D_ * CHUNKS * K_);  // 64*32*256 f32 = 2 MB
  float* nS = psum + (size_t)D_ * CHUNKS * DIM_;            // 128 KB

  k1_stream<<<D_ * CHUNKS, 256, 0, stream>>>(emb, cand, psum);
  k23_topk_samples<<<D_, 256, 0, stream>>>(emb, cand, psum, nS, out);
  k4_loss<<<P_, 256, 0, stream>>>(nS, negidx, out);
}